// Round 5
// baseline (540.161 us; speedup 1.0000x reference)
//
#include <hip/hip_runtime.h>
#include <math.h>

// Problem constants (B,N,M,F,K) = (32,256,64,128,64)
#define PB 32
#define PN 256
#define PM 64
#define PF 128
#define PK 64
#define ROWS (PB*PN)          // 8192 atom rows
#define NTOT (ROWS*PF)        // 1048576

typedef __attribute__((ext_vector_type(4))) float  floatx4;
typedef __attribute__((ext_vector_type(8))) short  shortx8;

__device__ __forceinline__ unsigned short f2b(float f){
    union { float f; unsigned int i; } c; c.f = f;
    unsigned int x = c.i;
    return (unsigned short)((x + 0x7fffu + ((x >> 16) & 1u)) >> 16);
}
__device__ __forceinline__ float bf2f(unsigned short u){
    union { unsigned int i; float f; } c; c.i = ((unsigned int)u) << 16; return c.f;
}
// shifted softplus, stable
__device__ __forceinline__ float sspf(float x){
    return fmaxf(x, 0.0f) + log1pf(expf(-fabsf(x))) - 0.69314718055994531f;
}
// pack 8 fp32 -> bf16x8
__device__ __forceinline__ shortx8 pack8(float4 a, float4 b){
    shortx8 r;
    r[0]=(short)f2b(a.x); r[1]=(short)f2b(a.y); r[2]=(short)f2b(a.z); r[3]=(short)f2b(a.w);
    r[4]=(short)f2b(b.x); r[5]=(short)f2b(b.y); r[6]=(short)f2b(b.z); r[7]=(short)f2b(b.w);
    return r;
}

// ---------------- kernel 1: xa = bf16(ssp(x)) ----------------
__global__ __launch_bounds__(256) void k_prep(const float* __restrict__ x,
                                              unsigned short* __restrict__ xa_b){
    int i = blockIdx.x * 256 + threadIdx.x;
    if (i < NTOT) xa_b[i] = f2b(sspf(x[i]));
}

// ---------------- kernel 2: message aggregation ----------------
// One block (4 waves) per (b,n). G = rbf(64x64) @ k2f_W^T (64x128) via MFMA,
// weights/rbf converted fp32->bf16 in-register; epilogue multiplies by
// gathered neighbor features and reduces over m via LDS partials.
__global__ __launch_bounds__(256) void k_msg(const float* __restrict__ rbf,
                                             const int* __restrict__ nbr,
                                             const float* __restrict__ Wk2f,
                                             const unsigned short* __restrict__ xa_b,
                                             float* __restrict__ xj){
    const int bid  = blockIdx.x;          // b*256 + n
    const int b    = bid >> 8;
    const int tid  = threadIdx.x;
    const int wave = tid >> 6;            // m-tile (16 m per wave)
    const int lane = tid & 63;
    const int quad = lane >> 4;
    const int l16  = lane & 15;

    __shared__ float xjpart[4][4][PF];    // [wave][quad][f]

    // A fragments: A[m = wave*16+l16][k = half*32 + quad*8 + j]
    const float* rrow = rbf + (size_t)bid * (PM*PK) + (size_t)(wave*16 + l16) * PK;
    shortx8 afrag0 = pack8(*(const float4*)(rrow + quad*8),
                           *(const float4*)(rrow + quad*8 + 4));
    shortx8 afrag1 = pack8(*(const float4*)(rrow + 32 + quad*8),
                           *(const float4*)(rrow + 32 + quad*8 + 4));

    // neighbor indices for the 4 C-rows this lane owns (m_local = quad*4 + r)
    int nb[4];
    #pragma unroll
    for (int r = 0; r < 4; ++r) nb[r] = nbr[bid*PM + wave*16 + quad*4 + r];

    #pragma unroll
    for (int ft = 0; ft < 8; ++ft){
        const float* wrow = Wk2f + (size_t)(ft*16 + l16) * PK;   // B[n=ft*16+l16][k]
        shortx8 b0 = pack8(*(const float4*)(wrow + quad*8),
                           *(const float4*)(wrow + quad*8 + 4));
        shortx8 b1 = pack8(*(const float4*)(wrow + 32 + quad*8),
                           *(const float4*)(wrow + 32 + quad*8 + 4));
        floatx4 acc = {0.f, 0.f, 0.f, 0.f};
        acc = __builtin_amdgcn_mfma_f32_16x16x32_bf16(afrag0, b0, acc, 0, 0, 0);
        acc = __builtin_amdgcn_mfma_f32_16x16x32_bf16(afrag1, b1, acc, 0, 0, 0);
        // C layout: col(f_local) = l16, row(m_local) = quad*4 + r
        float s = 0.f;
        #pragma unroll
        for (int r = 0; r < 4; ++r){
            float xv = bf2f(xa_b[((size_t)b*PN + nb[r])*PF + ft*16 + l16]);
            s += acc[r] * xv;
        }
        xjpart[wave][quad][ft*16 + l16] = s;   // partial over 4 m's
    }
    __syncthreads();
    if (tid < PF){
        float v = 0.f;
        #pragma unroll
        for (int w = 0; w < 4; ++w)
            #pragma unroll
            for (int q = 0; q < 4; ++q)
                v += xjpart[w][q][tid];
        xj[(size_t)bid*PF + tid] = v;
    }
}

// ---------------- kernel 3: generic chain stage ----------------
// z[row,f] = sum_k inb[row,k]*W[f,k] + bias[f]  (W fp32, cvt in-register)
// EP_S1  : out_f = ssp(z) + extra;          out_b = bf16(ssp(out_f))
// EP_T   : out_b = bf16(ssp(z))
// EP_RES : out_f = extra + z;               out_b = bf16(ssp(out_f))
// EP_GATE: out_f = gate[f]*x[row,f] + z;    out_b = bf16(ssp(out_f))
// EP_FIN : out_f = extra + z                (fp32 store to d_out)
// STRICT: callers never pass the same buffer as input and output.
#define EP_S1   0
#define EP_T    1
#define EP_RES  2
#define EP_GATE 3
#define EP_FIN  4

template <int MODE>
__global__ __launch_bounds__(256) void k_stage(const unsigned short* __restrict__ inb,
                                               const float* __restrict__ W,
                                               const float* __restrict__ bias,
                                               const float* __restrict__ extra,
                                               const float* __restrict__ xf,
                                               const float* __restrict__ gate,
                                               float* __restrict__ out_f,
                                               unsigned short* __restrict__ out_b){
    const int tid  = threadIdx.x;
    const int wave = tid >> 6;
    const int lane = tid & 63;
    const int quad = lane >> 4;
    const int l16  = lane & 15;
    const int mrow0 = (blockIdx.x * 4 + wave) * 16;

    const unsigned short* inrow = inb + (size_t)(mrow0 + l16) * PF;
    shortx8 a[4];
    #pragma unroll
    for (int ks = 0; ks < 4; ++ks)
        a[ks] = *(const shortx8*)(inrow + ks*32 + quad*8);

    floatx4 acc[8];
    #pragma unroll
    for (int ft = 0; ft < 8; ++ft){
        const float* wrow = W + (size_t)(ft*16 + l16) * PF;
        floatx4 c = {0.f, 0.f, 0.f, 0.f};
        #pragma unroll
        for (int ks = 0; ks < 4; ++ks){
            shortx8 bf = pack8(*(const float4*)(wrow + ks*32 + quad*8),
                               *(const float4*)(wrow + ks*32 + quad*8 + 4));
            c = __builtin_amdgcn_mfma_f32_16x16x32_bf16(a[ks], bf, c, 0, 0, 0);
        }
        acc[ft] = c;
    }

    #pragma unroll
    for (int ft = 0; ft < 8; ++ft){
        const int col = ft*16 + l16;
        const float bcol = bias[col];
        #pragma unroll
        for (int r = 0; r < 4; ++r){
            const int row = mrow0 + quad*4 + r;
            const size_t idx = (size_t)row * PF + col;
            const float z = acc[ft][r] + bcol;
            if (MODE == EP_T){
                out_b[idx] = f2b(sspf(z));
            } else if (MODE == EP_FIN){
                out_f[idx] = extra[idx] + z;           // fp32 final store
            } else {
                float of;
                if (MODE == EP_S1)        of = sspf(z) + extra[idx];
                else if (MODE == EP_RES)  of = extra[idx] + z;
                else /* EP_GATE */        of = gate[col] * xf[idx] + z;
                out_f[idx] = of;
                out_b[idx] = f2b(sspf(of));
            }
        }
    }
}

extern "C" void kernel_launch(void* const* d_in, const int* in_sizes, int n_in,
                              void* d_out, int out_size, void* d_ws, size_t ws_size,
                              hipStream_t stream){
    const float* x     = (const float*)d_in[0];
    const float* rbf   = (const float*)d_in[1];
    const int*   nbr   = (const int*)d_in[2];
    const float* k2fW  = (const float*)d_in[3];
    const float* Wi    = (const float*)d_in[4];
    const float* bi    = (const float*)d_in[5];
    const float* iW1   = (const float*)d_in[6];
    const float* ib1   = (const float*)d_in[7];
    const float* iW2   = (const float*)d_in[8];
    const float* ib2   = (const float*)d_in[9];
    const float* Wint  = (const float*)d_in[10];
    const float* bint  = (const float*)d_in[11];
    const float* ugate = (const float*)d_in[12];
    const float* aW1   = (const float*)d_in[13];
    const float* ab1   = (const float*)d_in[14];
    const float* aW2   = (const float*)d_in[15];
    const float* ab2   = (const float*)d_in[16];

    // 12 MB workspace, strict ping-pong (no kernel reads a buffer it writes):
    //   Af [0,4MB) fp32   Bf [4,8MB) fp32   T1 [8,10MB) bf16   T2 [10,12MB) bf16
    char* ws = (char*)d_ws;
    float*          Af = (float*)ws;
    float*          Bf = (float*)(ws + (4ull  << 20));
    unsigned short* T1 = (unsigned short*)(ws + (8ull  << 20));
    unsigned short* T2 = (unsigned short*)(ws + (10ull << 20));

    dim3 g(ROWS/64), blk(256);

    k_prep<<<NTOT/256, 256, 0, stream>>>(x, T1);                       // T1 = bf16(ssp(x))
    k_msg<<<PB*PN, 256, 0, stream>>>(rbf, nbr, k2fW, T1, Af);          // Af = xj

    // v = ssp(xa@Wi^T+bi) + xj : in T1,Af -> out Bf(v), T2(bf16 ssp v)
    k_stage<EP_S1><<<g, blk, 0, stream>>>(T1, Wi, bi, Af, nullptr, nullptr, Bf, T2);
    // interaction res blocks; carry alternates Bf->Af->Bf->Af
    k_stage<EP_T  ><<<g, blk, 0, stream>>>(T2, iW1 + 0*PF*PF, ib1 + 0*PF,
                                           nullptr, nullptr, nullptr, nullptr, T1);
    k_stage<EP_RES><<<g, blk, 0, stream>>>(T1, iW2 + 0*PF*PF, ib2 + 0*PF,
                                           Bf, nullptr, nullptr, Af, T2);
    k_stage<EP_T  ><<<g, blk, 0, stream>>>(T2, iW1 + 1*PF*PF, ib1 + 1*PF,
                                           nullptr, nullptr, nullptr, nullptr, T1);
    k_stage<EP_RES><<<g, blk, 0, stream>>>(T1, iW2 + 1*PF*PF, ib2 + 1*PF,
                                           Af, nullptr, nullptr, Bf, T2);
    k_stage<EP_T  ><<<g, blk, 0, stream>>>(T2, iW1 + 2*PF*PF, ib1 + 2*PF,
                                           nullptr, nullptr, nullptr, nullptr, T1);
    k_stage<EP_RES><<<g, blk, 0, stream>>>(T1, iW2 + 2*PF*PF, ib2 + 2*PF,
                                           Bf, nullptr, nullptr, Af, T2);
    // out = u_gate*x + ssp(v)@Wint^T + bint : in T2,x -> out Bf(out), T1
    k_stage<EP_GATE><<<g, blk, 0, stream>>>(T2, Wint, bint, nullptr, x, ugate, Bf, T1);
    // atom res block 0: in T1 -> T2 ; in T2,Bf -> Af(out'), T1
    k_stage<EP_T  ><<<g, blk, 0, stream>>>(T1, aW1 + 0*PF*PF, ab1 + 0*PF,
                                           nullptr, nullptr, nullptr, nullptr, T2);
    k_stage<EP_RES><<<g, blk, 0, stream>>>(T2, aW2 + 0*PF*PF, ab2 + 0*PF,
                                           Bf, nullptr, nullptr, Af, T1);
    // atom res block 1: in T1 -> T2 ; final fp32: d_out = Af + z
    k_stage<EP_T  ><<<g, blk, 0, stream>>>(T1, aW1 + 1*PF*PF, ab1 + 1*PF,
                                           nullptr, nullptr, nullptr, nullptr, T2);
    k_stage<EP_FIN><<<g, blk, 0, stream>>>(T2, aW2 + 1*PF*PF, ab2 + 1*PF,
                                           Af, nullptr, nullptr, (float*)d_out, nullptr);
}

// Round 6
// 323.237 us; speedup vs baseline: 1.6711x; 1.6711x over previous
//
#include <hip/hip_runtime.h>
#include <math.h>

// Problem constants (B,N,M,F,K) = (32,256,64,128,64)
#define PB 32
#define PN 256
#define PM 64
#define PF 128
#define PK 64
#define ROWS (PB*PN)          // 8192 atom rows
#define NTOT (ROWS*PF)        // 1048576

// bf16 weight arena offsets (elements)
#define OFF_K2F  0
#define OFF_WI   8192
#define OFF_IW1  24576
#define OFF_IW2  73728
#define OFF_WINT 122880
#define OFF_AW1  139264
#define OFF_AW2  172032
#define TOTAL_W  204800

#define XPITCH 136            // LDS row pitch (ushorts): 272 B, 16B-aligned, bank-skewed

typedef __attribute__((ext_vector_type(4))) float  floatx4;
typedef __attribute__((ext_vector_type(8))) short  shortx8;

__device__ __forceinline__ unsigned short f2b(float f){
    union { float f; unsigned int i; } c; c.f = f;
    unsigned int x = c.i;
    return (unsigned short)((x + 0x7fffu + ((x >> 16) & 1u)) >> 16);
}
__device__ __forceinline__ float bf2f(unsigned short u){
    union { unsigned int i; float f; } c; c.i = ((unsigned int)u) << 16; return c.f;
}
__device__ __forceinline__ float sspf(float x){
    return fmaxf(x, 0.0f) + log1pf(expf(-fabsf(x))) - 0.69314718055994531f;
}
__device__ __forceinline__ shortx8 pack8(float4 a, float4 b){
    shortx8 r;
    r[0]=(short)f2b(a.x); r[1]=(short)f2b(a.y); r[2]=(short)f2b(a.z); r[3]=(short)f2b(a.w);
    r[4]=(short)f2b(b.x); r[5]=(short)f2b(b.y); r[6]=(short)f2b(b.z); r[7]=(short)f2b(b.w);
    return r;
}

// ---------------- kernel 1: xa_b = bf16(ssp(x)); weights -> bf16 arena ----------------
__global__ __launch_bounds__(256) void k_pre(const float* __restrict__ x,
                                             const float* __restrict__ k2f,
                                             const float* __restrict__ Wi,
                                             const float* __restrict__ iW1,
                                             const float* __restrict__ iW2,
                                             const float* __restrict__ Wint,
                                             const float* __restrict__ aW1,
                                             const float* __restrict__ aW2,
                                             unsigned short* __restrict__ xa_b,
                                             unsigned short* __restrict__ Wb){
    int i = blockIdx.x * 256 + threadIdx.x;
    if (i < NTOT){ xa_b[i] = f2b(sspf(x[i])); return; }
    int j = i - NTOT;
    if (j >= TOTAL_W) return;
    float v;
    if      (j < OFF_WI)   v = k2f[j - OFF_K2F];
    else if (j < OFF_IW1)  v = Wi[j - OFF_WI];
    else if (j < OFF_IW2)  v = iW1[j - OFF_IW1];
    else if (j < OFF_WINT) v = iW2[j - OFF_IW2];
    else if (j < OFF_AW1)  v = Wint[j - OFF_WINT];
    else if (j < OFF_AW2)  v = aW1[j - OFF_AW1];
    else                   v = aW2[j - OFF_AW2];
    Wb[j] = f2b(v);
}

// ---------------- kernel 2: message aggregation (LDS-staged gather) ----------------
__global__ __launch_bounds__(256) void k_msg(const float* __restrict__ rbf,
                                             const int* __restrict__ nbr,
                                             const unsigned short* __restrict__ Wk2f, // bf16
                                             const unsigned short* __restrict__ xa_b,
                                             float* __restrict__ xj){
    const int bid  = blockIdx.x;          // b*256 + n
    const int b    = bid >> 8;
    const int tid  = threadIdx.x;
    const int wave = tid >> 6;            // m-tile (16 m per wave)
    const int lane = tid & 63;
    const int quad = lane >> 4;
    const int l16  = lane & 15;

    __shared__ unsigned short Xn[PM * XPITCH];  // 17 KB gathered neighbor rows
    __shared__ float xjpart[4][PF];             // 2 KB

    // Phase 1a: A fragments from rbf (coalesced fp32, pack in-register)
    const float* rrow = rbf + (size_t)bid * (PM*PK) + (size_t)(wave*16 + l16) * PK;
    shortx8 afrag0 = pack8(*(const float4*)(rrow + quad*8),
                           *(const float4*)(rrow + quad*8 + 4));
    shortx8 afrag1 = pack8(*(const float4*)(rrow + 32 + quad*8),
                           *(const float4*)(rrow + 32 + quad*8 + 4));

    // Phase 1b: gather 64 neighbor rows into LDS (4 threads per row, 64 B each)
    {
        const int r = tid >> 2;           // 0..63
        const int p = tid & 3;            // 64-B chunk
        const int row = nbr[bid*PM + r];
        const uint4* gsrc = (const uint4*)(xa_b + ((size_t)b*PN + row)*PF) + p*4;
        uint4* ldst = (uint4*)((char*)Xn + r*(XPITCH*2) + p*64);
        #pragma unroll
        for (int j = 0; j < 4; ++j) ldst[j] = gsrc[j];
    }
    __syncthreads();

    // Phase 2: MFMA + LDS-sourced multiply-reduce; per-ft partials in registers
    float s[8];
    #pragma unroll
    for (int ft = 0; ft < 8; ++ft) s[ft] = 0.f;

    #pragma unroll
    for (int ft = 0; ft < 8; ++ft){
        const unsigned short* wrow = Wk2f + (size_t)(ft*16 + l16) * PK;
        shortx8 b0 = *(const shortx8*)(wrow +  0 + quad*8);
        shortx8 b1 = *(const shortx8*)(wrow + 32 + quad*8);
        floatx4 acc = {0.f, 0.f, 0.f, 0.f};
        acc = __builtin_amdgcn_mfma_f32_16x16x32_bf16(afrag0, b0, acc, 0, 0, 0);
        acc = __builtin_amdgcn_mfma_f32_16x16x32_bf16(afrag1, b1, acc, 0, 0, 0);
        // C layout: col(f_local)=l16, row(m_local)=quad*4+r
        #pragma unroll
        for (int r = 0; r < 4; ++r){
            float xv = bf2f(Xn[(wave*16 + quad*4 + r)*XPITCH + ft*16 + l16]);
            s[ft] += acc[r] * xv;
        }
    }
    // reduce over quads (m) via shfl, lane quad==0 holds the wave partial
    #pragma unroll
    for (int ft = 0; ft < 8; ++ft){
        float v = s[ft];
        v += __shfl_xor(v, 16, 64);
        v += __shfl_xor(v, 32, 64);
        if (quad == 0) xjpart[wave][ft*16 + l16] = v;
    }
    __syncthreads();
    if (tid < PF){
        float v = xjpart[0][tid] + xjpart[1][tid] + xjpart[2][tid] + xjpart[3][tid];
        xj[(size_t)bid*PF + tid] = v;
    }
}

// ---------------- kernel 3: fused 12-stage chain ----------------
// One block = one 16-row tile through the ENTIRE per-atom chain. 4 waves split
// the 8 ft-columns (2 each). C-layout -> A-layout between stages via shared
// LDS tile (pitch XPITCH). Carry V stays fp32 in registers.
__device__ __forceinline__ void gemm2(const unsigned short* __restrict__ W,
                                      int l16, int quad, int ftbase,
                                      const shortx8 a[4], floatx4 acc[2]){
    #pragma unroll
    for (int f = 0; f < 2; ++f){
        const unsigned short* wrow = W + (size_t)((ftbase+f)*16 + l16) * PF;
        floatx4 c = {0.f, 0.f, 0.f, 0.f};
        #pragma unroll
        for (int ks = 0; ks < 4; ++ks){
            shortx8 bf = *(const shortx8*)(wrow + ks*32 + quad*8);
            c = __builtin_amdgcn_mfma_f32_16x16x32_bf16(a[ks], bf, c, 0, 0, 0);
        }
        acc[f] = c;
    }
}

__device__ __forceinline__ void relayout(unsigned short* Tls,
                                         const unsigned short t16[8],
                                         int l16, int quad, int ftbase,
                                         shortx8 a[4]){
    __syncthreads();   // WAR: previous stage's reads done
    #pragma unroll
    for (int f = 0; f < 2; ++f)
        #pragma unroll
        for (int r = 0; r < 4; ++r)
            Tls[(quad*4 + r)*XPITCH + (ftbase+f)*16 + l16] = t16[f*4 + r];
    __syncthreads();   // RAW
    #pragma unroll
    for (int ks = 0; ks < 4; ++ks)
        a[ks] = *(const shortx8*)(Tls + l16*XPITCH + ks*32 + quad*8);
}

__global__ __launch_bounds__(256) void k_chain(const unsigned short* __restrict__ xa_b,
                                               const float* __restrict__ xj,
                                               const float* __restrict__ x,
                                               const unsigned short* __restrict__ Wb,
                                               const float* __restrict__ bi,
                                               const float* __restrict__ ib1,
                                               const float* __restrict__ ib2,
                                               const float* __restrict__ bint,
                                               const float* __restrict__ ugate,
                                               const float* __restrict__ ab1,
                                               const float* __restrict__ ab2,
                                               float* __restrict__ out){
    const int tid  = threadIdx.x;
    const int wave = tid >> 6;
    const int lane = tid & 63;
    const int quad = lane >> 4;
    const int l16  = lane & 15;
    const int ftb  = wave*2;              // this wave's 2 ft-columns
    const int row0 = blockIdx.x * 16;

    __shared__ unsigned short Tls[16 * XPITCH];   // 4.25 KB

    int col[2];
    #pragma unroll
    for (int f = 0; f < 2; ++f) col[f] = (ftb+f)*16 + l16;

    // initial A fragments: bf16(ssp(x)) rows, A-layout direct from global
    const unsigned short* inrow = xa_b + (size_t)(row0 + l16) * PF;
    shortx8 a[4];
    #pragma unroll
    for (int ks = 0; ks < 4; ++ks)
        a[ks] = *(const shortx8*)(inrow + ks*32 + quad*8);

    floatx4 acc[2];
    float V[8];                 // fp32 carry, [f*4+r]
    unsigned short t16[8];

    // ---- stage A: v = ssp(xa@Wi^T + bi) + xj ----
    gemm2(Wb + OFF_WI, l16, quad, ftb, a, acc);
    #pragma unroll
    for (int f = 0; f < 2; ++f)
        #pragma unroll
        for (int r = 0; r < 4; ++r){
            size_t idx = (size_t)(row0 + quad*4 + r)*PF + col[f];
            float of = sspf(acc[f][r] + bi[col[f]]) + xj[idx];
            V[f*4+r] = of;
            t16[f*4+r] = f2b(sspf(of));
        }
    relayout(Tls, t16, l16, quad, ftb, a);

    // ---- 3 interaction residual blocks ----
    for (int l = 0; l < 3; ++l){
        gemm2(Wb + OFF_IW1 + l*PF*PF, l16, quad, ftb, a, acc);
        #pragma unroll
        for (int f = 0; f < 2; ++f)
            #pragma unroll
            for (int r = 0; r < 4; ++r)
                t16[f*4+r] = f2b(sspf(acc[f][r] + ib1[l*PF + col[f]]));
        relayout(Tls, t16, l16, quad, ftb, a);

        gemm2(Wb + OFF_IW2 + l*PF*PF, l16, quad, ftb, a, acc);
        #pragma unroll
        for (int f = 0; f < 2; ++f)
            #pragma unroll
            for (int r = 0; r < 4; ++r){
                V[f*4+r] += acc[f][r] + ib2[l*PF + col[f]];
                t16[f*4+r] = f2b(sspf(V[f*4+r]));
            }
        relayout(Tls, t16, l16, quad, ftb, a);
    }

    // ---- gate: out = u_gate*x + ssp(v)@Wint^T + bint ----
    gemm2(Wb + OFF_WINT, l16, quad, ftb, a, acc);
    #pragma unroll
    for (int f = 0; f < 2; ++f)
        #pragma unroll
        for (int r = 0; r < 4; ++r){
            size_t idx = (size_t)(row0 + quad*4 + r)*PF + col[f];
            float o = ugate[col[f]] * x[idx] + acc[f][r] + bint[col[f]];
            V[f*4+r] = o;
            t16[f*4+r] = f2b(sspf(o));
        }
    relayout(Tls, t16, l16, quad, ftb, a);

    // ---- 2 atom residual blocks (last one stores fp32) ----
    #pragma unroll
    for (int l = 0; l < 2; ++l){
        gemm2(Wb + OFF_AW1 + l*PF*PF, l16, quad, ftb, a, acc);
        #pragma unroll
        for (int f = 0; f < 2; ++f)
            #pragma unroll
            for (int r = 0; r < 4; ++r)
                t16[f*4+r] = f2b(sspf(acc[f][r] + ab1[l*PF + col[f]]));
        relayout(Tls, t16, l16, quad, ftb, a);

        gemm2(Wb + OFF_AW2 + l*PF*PF, l16, quad, ftb, a, acc);
        if (l == 0){
            #pragma unroll
            for (int f = 0; f < 2; ++f)
                #pragma unroll
                for (int r = 0; r < 4; ++r){
                    V[f*4+r] += acc[f][r] + ab2[l*PF + col[f]];
                    t16[f*4+r] = f2b(sspf(V[f*4+r]));
                }
            relayout(Tls, t16, l16, quad, ftb, a);
        } else {
            #pragma unroll
            for (int f = 0; f < 2; ++f)
                #pragma unroll
                for (int r = 0; r < 4; ++r){
                    size_t idx = (size_t)(row0 + quad*4 + r)*PF + col[f];
                    out[idx] = V[f*4+r] + acc[f][r] + ab2[l*PF + col[f]];
                }
        }
    }
}

extern "C" void kernel_launch(void* const* d_in, const int* in_sizes, int n_in,
                              void* d_out, int out_size, void* d_ws, size_t ws_size,
                              hipStream_t stream){
    const float* x     = (const float*)d_in[0];
    const float* rbf   = (const float*)d_in[1];
    const int*   nbr   = (const int*)d_in[2];
    const float* k2fW  = (const float*)d_in[3];
    const float* Wi    = (const float*)d_in[4];
    const float* bi    = (const float*)d_in[5];
    const float* iW1   = (const float*)d_in[6];
    const float* ib1   = (const float*)d_in[7];
    const float* iW2   = (const float*)d_in[8];
    const float* ib2   = (const float*)d_in[9];
    const float* Wint  = (const float*)d_in[10];
    const float* bint  = (const float*)d_in[11];
    const float* ugate = (const float*)d_in[12];
    const float* aW1   = (const float*)d_in[13];
    const float* ab1   = (const float*)d_in[14];
    const float* aW2   = (const float*)d_in[15];
    const float* ab2   = (const float*)d_in[16];

    // Workspace (~6.4 MB): xa_b [0,2MB) bf16; xj [2,6MB) fp32; Wb arena [6MB,+400K)
    char* ws = (char*)d_ws;
    unsigned short* xa_b = (unsigned short*)ws;
    float*          xj   = (float*)(ws + (2ull << 20));
    unsigned short* Wb   = (unsigned short*)(ws + (6ull << 20));

    k_pre<<<(NTOT + TOTAL_W + 255)/256, 256, 0, stream>>>(
        x, k2fW, Wi, iW1, iW2, Wint, aW1, aW2, xa_b, Wb);
    k_msg<<<PB*PN, 256, 0, stream>>>(rbf, nbr, Wb + OFF_K2F, xa_b, xj);
    k_chain<<<ROWS/16, 256, 0, stream>>>(xa_b, xj, x, Wb,
                                         bi, ib1, ib2, bint, ugate, ab1, ab2,
                                         (float*)d_out);
}

// Round 7
// 316.079 us; speedup vs baseline: 1.7089x; 1.0226x over previous
//
#include <hip/hip_runtime.h>
#include <math.h>

// Problem constants (B,N,M,F,K) = (32,256,64,128,64)
#define PB 32
#define PN 256
#define PM 64
#define PF 128
#define PK 64
#define ROWS (PB*PN)          // 8192 atom rows
#define NTOT (ROWS*PF)        // 1048576

// bf16 weight arena offsets (elements)
#define OFF_K2F  0
#define OFF_WI   8192
#define OFF_IW1  24576
#define OFF_IW2  73728
#define OFF_WINT 122880
#define OFF_AW1  139264
#define OFF_AW2  172032
#define TOTAL_W  204800

#define XPITCH 136            // LDS row pitch (ushorts)

typedef __attribute__((ext_vector_type(4))) float  floatx4;
typedef __attribute__((ext_vector_type(8))) short  shortx8;

__device__ __forceinline__ unsigned short f2b(float f){
    union { float f; unsigned int i; } c; c.f = f;
    unsigned int x = c.i;
    return (unsigned short)((x + 0x7fffu + ((x >> 16) & 1u)) >> 16);
}
__device__ __forceinline__ float bf2f(unsigned short u){
    union { unsigned int i; float f; } c; c.i = ((unsigned int)u) << 16; return c.f;
}
__device__ __forceinline__ float sspf(float x){
    return fmaxf(x, 0.0f) + log1pf(expf(-fabsf(x))) - 0.69314718055994531f;
}
__device__ __forceinline__ shortx8 pack8(float4 a, float4 b){
    shortx8 r;
    r[0]=(short)f2b(a.x); r[1]=(short)f2b(a.y); r[2]=(short)f2b(a.z); r[3]=(short)f2b(a.w);
    r[4]=(short)f2b(b.x); r[5]=(short)f2b(b.y); r[6]=(short)f2b(b.z); r[7]=(short)f2b(b.w);
    return r;
}

// ---- kernel 1: xa_f = ssp(x) fp32; xa_b = bf16(ssp(x)); weights -> bf16 arena ----
__global__ __launch_bounds__(256) void k_pre(const float* __restrict__ x,
                                             const float* __restrict__ k2f,
                                             const float* __restrict__ Wi,
                                             const float* __restrict__ iW1,
                                             const float* __restrict__ iW2,
                                             const float* __restrict__ Wint,
                                             const float* __restrict__ aW1,
                                             const float* __restrict__ aW2,
                                             float* __restrict__ xa_f,
                                             unsigned short* __restrict__ xa_b,
                                             unsigned short* __restrict__ Wb){
    int i = blockIdx.x * 256 + threadIdx.x;
    if (i < NTOT){
        float v = sspf(x[i]);
        xa_f[i] = v;
        xa_b[i] = f2b(v);
        return;
    }
    int j = i - NTOT;
    if (j >= TOTAL_W) return;
    float v;
    if      (j < OFF_WI)   v = k2f[j - OFF_K2F];
    else if (j < OFF_IW1)  v = Wi[j - OFF_WI];
    else if (j < OFF_IW2)  v = iW1[j - OFF_IW1];
    else if (j < OFF_WINT) v = iW2[j - OFF_IW2];
    else if (j < OFF_AW1)  v = Wint[j - OFF_WINT];
    else if (j < OFF_AW2)  v = aW1[j - OFF_AW1];
    else                   v = aW2[j - OFF_AW2];
    Wb[j] = f2b(v);
}

// ---------------- kernel 2: message aggregation, wave-per-atom ----------------
// No LDS, no __syncthreads. Each wave: full 64x64 @ 64x128 for one atom in
// 4 m-tiles; neighbor indices live one-per-lane, fetched via __shfl;
// gather reads fp32 xa_f; quad-reduction via shfl_xor.
__global__ __launch_bounds__(256) void k_msg(const float* __restrict__ rbf,
                                             const int* __restrict__ nbr,
                                             const unsigned short* __restrict__ Wk2f, // bf16
                                             const float* __restrict__ xa_f,
                                             float* __restrict__ xj){
    const int tid  = threadIdx.x;
    const int bid  = blockIdx.x * 4 + (tid >> 6);   // atom id = b*256+n
    const int b    = bid >> 8;
    const int lane = tid & 63;
    const int quad = lane >> 4;
    const int l16  = lane & 15;

    const int nbv = nbr[bid*PM + lane];             // one neighbor index per lane
    const float* xab = xa_f + (size_t)b * PN * PF;

    float s[8];
    #pragma unroll
    for (int ft = 0; ft < 8; ++ft) s[ft] = 0.f;

    const float* rbase = rbf + (size_t)bid * (PM*PK);

    #pragma unroll
    for (int t = 0; t < 4; ++t){
        // A fragments for m-rows [t*16, t*16+16): A[m=l16][k=quad*8+j | 32+quad*8+j]
        const float* rrow = rbase + (size_t)(t*16 + l16) * PK;
        shortx8 afrag0 = pack8(*(const float4*)(rrow + quad*8),
                               *(const float4*)(rrow + quad*8 + 4));
        shortx8 afrag1 = pack8(*(const float4*)(rrow + 32 + quad*8),
                               *(const float4*)(rrow + 32 + quad*8 + 4));

        // neighbor rows this lane needs in C-layout (m_local = quad*4 + r)
        const int mb = t*16 + quad*4;
        int idx0 = __shfl(nbv, mb + 0, 64);
        int idx1 = __shfl(nbv, mb + 1, 64);
        int idx2 = __shfl(nbv, mb + 2, 64);
        int idx3 = __shfl(nbv, mb + 3, 64);

        #pragma unroll
        for (int ft = 0; ft < 8; ++ft){
            const unsigned short* wrow = Wk2f + (size_t)(ft*16 + l16) * PK;
            shortx8 b0 = *(const shortx8*)(wrow +  0 + quad*8);
            shortx8 b1 = *(const shortx8*)(wrow + 32 + quad*8);
            floatx4 acc = {0.f, 0.f, 0.f, 0.f};
            acc = __builtin_amdgcn_mfma_f32_16x16x32_bf16(afrag0, b0, acc, 0, 0, 0);
            acc = __builtin_amdgcn_mfma_f32_16x16x32_bf16(afrag1, b1, acc, 0, 0, 0);
            const int col = ft*16 + l16;
            s[ft] += acc[0] * xab[(size_t)idx0*PF + col];
            s[ft] += acc[1] * xab[(size_t)idx1*PF + col];
            s[ft] += acc[2] * xab[(size_t)idx2*PF + col];
            s[ft] += acc[3] * xab[(size_t)idx3*PF + col];
        }
    }

    // reduce over the 4 quads (m) and store
    #pragma unroll
    for (int ft = 0; ft < 8; ++ft){
        float v = s[ft];
        v += __shfl_xor(v, 16, 64);
        v += __shfl_xor(v, 32, 64);
        if (quad == 0) xj[(size_t)bid*PF + ft*16 + l16] = v;
    }
}

// ---------------- kernel 3: fused 12-stage chain (double-buffered LDS) ----------------
__device__ __forceinline__ void gemm2(const unsigned short* __restrict__ W,
                                      int l16, int quad, int ftbase,
                                      const shortx8 a[4], floatx4 acc[2]){
    #pragma unroll
    for (int f = 0; f < 2; ++f){
        const unsigned short* wrow = W + (size_t)((ftbase+f)*16 + l16) * PF;
        floatx4 c = {0.f, 0.f, 0.f, 0.f};
        #pragma unroll
        for (int ks = 0; ks < 4; ++ks){
            shortx8 bf = *(const shortx8*)(wrow + ks*32 + quad*8);
            c = __builtin_amdgcn_mfma_f32_16x16x32_bf16(a[ks], bf, c, 0, 0, 0);
        }
        acc[f] = c;
    }
}

// write C-layout t16 into buffer p, barrier once, read back A-frags
__device__ __forceinline__ void relayout(unsigned short* Tls,   // base of buffer p
                                         const unsigned short t16[8],
                                         int l16, int quad, int ftbase,
                                         shortx8 a[4]){
    #pragma unroll
    for (int f = 0; f < 2; ++f)
        #pragma unroll
        for (int r = 0; r < 4; ++r)
            Tls[(quad*4 + r)*XPITCH + (ftbase+f)*16 + l16] = t16[f*4 + r];
    __syncthreads();   // RAW; WAR across stages handled by double-buffering
    #pragma unroll
    for (int ks = 0; ks < 4; ++ks)
        a[ks] = *(const shortx8*)(Tls + l16*XPITCH + ks*32 + quad*8);
}

__global__ __launch_bounds__(256) void k_chain(const unsigned short* __restrict__ xa_b,
                                               const float* __restrict__ xj,
                                               const float* __restrict__ x,
                                               const unsigned short* __restrict__ Wb,
                                               const float* __restrict__ bi,
                                               const float* __restrict__ ib1,
                                               const float* __restrict__ ib2,
                                               const float* __restrict__ bint,
                                               const float* __restrict__ ugate,
                                               const float* __restrict__ ab1,
                                               const float* __restrict__ ab2,
                                               float* __restrict__ out){
    const int tid  = threadIdx.x;
    const int wave = tid >> 6;
    const int lane = tid & 63;
    const int quad = lane >> 4;
    const int l16  = lane & 15;
    const int ftb  = wave*2;
    const int row0 = blockIdx.x * 16;

    __shared__ unsigned short Tls[2][16 * XPITCH];   // 8.5 KB double buffer
    int p = 0;

    int col[2];
    #pragma unroll
    for (int f = 0; f < 2; ++f) col[f] = (ftb+f)*16 + l16;

    const unsigned short* inrow = xa_b + (size_t)(row0 + l16) * PF;
    shortx8 a[4];
    #pragma unroll
    for (int ks = 0; ks < 4; ++ks)
        a[ks] = *(const shortx8*)(inrow + ks*32 + quad*8);

    floatx4 acc[2];
    float V[8];
    unsigned short t16[8];

    // ---- stage A: v = ssp(xa@Wi^T + bi) + xj ----
    gemm2(Wb + OFF_WI, l16, quad, ftb, a, acc);
    #pragma unroll
    for (int f = 0; f < 2; ++f)
        #pragma unroll
        for (int r = 0; r < 4; ++r){
            size_t idx = (size_t)(row0 + quad*4 + r)*PF + col[f];
            float of = sspf(acc[f][r] + bi[col[f]]) + xj[idx];
            V[f*4+r] = of;
            t16[f*4+r] = f2b(sspf(of));
        }
    relayout(Tls[p], t16, l16, quad, ftb, a); p ^= 1;

    // ---- 3 interaction residual blocks ----
    for (int l = 0; l < 3; ++l){
        gemm2(Wb + OFF_IW1 + l*PF*PF, l16, quad, ftb, a, acc);
        #pragma unroll
        for (int f = 0; f < 2; ++f)
            #pragma unroll
            for (int r = 0; r < 4; ++r)
                t16[f*4+r] = f2b(sspf(acc[f][r] + ib1[l*PF + col[f]]));
        relayout(Tls[p], t16, l16, quad, ftb, a); p ^= 1;

        gemm2(Wb + OFF_IW2 + l*PF*PF, l16, quad, ftb, a, acc);
        #pragma unroll
        for (int f = 0; f < 2; ++f)
            #pragma unroll
            for (int r = 0; r < 4; ++r){
                V[f*4+r] += acc[f][r] + ib2[l*PF + col[f]];
                t16[f*4+r] = f2b(sspf(V[f*4+r]));
            }
        relayout(Tls[p], t16, l16, quad, ftb, a); p ^= 1;
    }

    // ---- gate: out = u_gate*x + ssp(v)@Wint^T + bint ----
    gemm2(Wb + OFF_WINT, l16, quad, ftb, a, acc);
    #pragma unroll
    for (int f = 0; f < 2; ++f)
        #pragma unroll
        for (int r = 0; r < 4; ++r){
            size_t idx = (size_t)(row0 + quad*4 + r)*PF + col[f];
            float o = ugate[col[f]] * x[idx] + acc[f][r] + bint[col[f]];
            V[f*4+r] = o;
            t16[f*4+r] = f2b(sspf(o));
        }
    relayout(Tls[p], t16, l16, quad, ftb, a); p ^= 1;

    // ---- 2 atom residual blocks ----
    #pragma unroll
    for (int l = 0; l < 2; ++l){
        gemm2(Wb + OFF_AW1 + l*PF*PF, l16, quad, ftb, a, acc);
        #pragma unroll
        for (int f = 0; f < 2; ++f)
            #pragma unroll
            for (int r = 0; r < 4; ++r)
                t16[f*4+r] = f2b(sspf(acc[f][r] + ab1[l*PF + col[f]]));
        relayout(Tls[p], t16, l16, quad, ftb, a); p ^= 1;

        gemm2(Wb + OFF_AW2 + l*PF*PF, l16, quad, ftb, a, acc);
        if (l == 0){
            #pragma unroll
            for (int f = 0; f < 2; ++f)
                #pragma unroll
                for (int r = 0; r < 4; ++r){
                    V[f*4+r] += acc[f][r] + ab2[l*PF + col[f]];
                    t16[f*4+r] = f2b(sspf(V[f*4+r]));
                }
            relayout(Tls[p], t16, l16, quad, ftb, a); p ^= 1;
        } else {
            #pragma unroll
            for (int f = 0; f < 2; ++f)
                #pragma unroll
                for (int r = 0; r < 4; ++r){
                    size_t idx = (size_t)(row0 + quad*4 + r)*PF + col[f];
                    out[idx] = V[f*4+r] + acc[f][r] + ab2[l*PF + col[f]];
                }
        }
    }
}

extern "C" void kernel_launch(void* const* d_in, const int* in_sizes, int n_in,
                              void* d_out, int out_size, void* d_ws, size_t ws_size,
                              hipStream_t stream){
    const float* x     = (const float*)d_in[0];
    const float* rbf   = (const float*)d_in[1];
    const int*   nbr   = (const int*)d_in[2];
    const float* k2fW  = (const float*)d_in[3];
    const float* Wi    = (const float*)d_in[4];
    const float* bi    = (const float*)d_in[5];
    const float* iW1   = (const float*)d_in[6];
    const float* ib1   = (const float*)d_in[7];
    const float* iW2   = (const float*)d_in[8];
    const float* ib2   = (const float*)d_in[9];
    const float* Wint  = (const float*)d_in[10];
    const float* bint  = (const float*)d_in[11];
    const float* ugate = (const float*)d_in[12];
    const float* aW1   = (const float*)d_in[13];
    const float* ab1   = (const float*)d_in[14];
    const float* aW2   = (const float*)d_in[15];
    const float* ab2   = (const float*)d_in[16];

    // Workspace (~10.4 MB):
    //   xa_b [0,2MB) bf16 ; xa_f [2,6MB) fp32 ; xj [6,10MB) fp32 ; Wb [10MB,+400K)
    char* ws = (char*)d_ws;
    unsigned short* xa_b = (unsigned short*)ws;
    float*          xa_f = (float*)(ws + (2ull  << 20));
    float*          xj   = (float*)(ws + (6ull  << 20));
    unsigned short* Wb   = (unsigned short*)(ws + (10ull << 20));

    k_pre<<<(NTOT + TOTAL_W + 255)/256, 256, 0, stream>>>(
        x, k2fW, Wi, iW1, iW2, Wint, aW1, aW2, xa_f, xa_b, Wb);
    k_msg<<<ROWS/4, 256, 0, stream>>>(rbf, nbr, Wb + OFF_K2F, xa_f, xj);
    k_chain<<<ROWS/16, 256, 0, stream>>>(xa_b, xj, x, Wb,
                                         bi, ib1, ib2, bint, ugate, ab1, ab2,
                                         (float*)d_out);
}